// Round 1
// baseline (58.178 us; speedup 1.0000x reference)
//
#include <hip/hip_runtime.h>

#define MASK_BLOCKS 1024
#define GAMMA 0.5f
#define SMOOTH 1.0f

// ---------------------------------------------------------------------------
// Kernel A: 5-way sum over the three masks (classic, gt, snake).
// Deterministic: per-block partial sums written to ws, no atomics.
// ---------------------------------------------------------------------------
__global__ __launch_bounds__(256) void mask_sums_kernel(
    const float4* __restrict__ g4, const float4* __restrict__ s4,
    const float4* __restrict__ c4, float* __restrict__ psum, int n4)
{
    float s_cg = 0.f, s_cs = 0.f, s_c = 0.f, s_g = 0.f, s_s = 0.f;
    int stride = gridDim.x * blockDim.x;
    for (int i = blockIdx.x * blockDim.x + threadIdx.x; i < n4; i += stride) {
        float4 g = g4[i];
        float4 s = s4[i];
        float4 c = c4[i];
        s_cg += c.x * g.x + c.y * g.y + c.z * g.z + c.w * g.w;
        s_cs += c.x * s.x + c.y * s.y + c.z * s.z + c.w * s.w;
        s_c  += c.x + c.y + c.z + c.w;
        s_g  += g.x + g.y + g.z + g.w;
        s_s  += s.x + s.y + s.z + s.w;
    }
#pragma unroll
    for (int off = 32; off > 0; off >>= 1) {
        s_cg += __shfl_down(s_cg, off);
        s_cs += __shfl_down(s_cs, off);
        s_c  += __shfl_down(s_c,  off);
        s_g  += __shfl_down(s_g,  off);
        s_s  += __shfl_down(s_s,  off);
    }
    __shared__ float red[4][5];
    int lane = threadIdx.x & 63;
    int wid  = threadIdx.x >> 6;
    if (lane == 0) {
        red[wid][0] = s_cg; red[wid][1] = s_cs; red[wid][2] = s_c;
        red[wid][3] = s_g;  red[wid][4] = s_s;
    }
    __syncthreads();
    if (threadIdx.x == 0) {
#pragma unroll
        for (int k = 0; k < 5; ++k) {
            float a = red[0][k] + red[1][k] + red[2][k] + red[3][k];
            psum[k * gridDim.x + blockIdx.x] = a;
        }
    }
}

// ---------------------------------------------------------------------------
// Kernel B: per-batch cyclic-shift MSE minima.
// One block per batch b; thread t = shift s. rolls[s][j] = x[(j-s) % n].
// seg: s==0 uses (scs - gtc); s>=1 uses (sgs - roll(gtc,s)).
// cons: all s use (scs - roll(cc,s)).
// ---------------------------------------------------------------------------
__global__ __launch_bounds__(256) void contour_kernel(
    const float2* __restrict__ gtc, const float2* __restrict__ sgs,
    const float2* __restrict__ scs, const float2* __restrict__ cc,
    float* __restrict__ seg_min, float* __restrict__ cons_min)
{
    __shared__ float gx[256], gy[256];   // ground_truth_contour
    __shared__ float ax[256], ay[256];   // snake_GT_size
    __shared__ float px[256], py[256];   // snake_classic_size
    __shared__ float cx[256], cy[256];   // classic_contour
    int b = blockIdx.x;
    int t = threadIdx.x;
    float2 v;
    v = gtc[b * 256 + t]; gx[t] = v.x; gy[t] = v.y;
    v = sgs[b * 256 + t]; ax[t] = v.x; ay[t] = v.y;
    v = scs[b * 256 + t]; px[t] = v.x; py[t] = v.y;
    v = cc [b * 256 + t]; cx[t] = v.x; cy[t] = v.y;
    __syncthreads();

    // shift-0 seg candidate compares snake_classic_size, others snake_GT_size
    const float* sx = (t == 0) ? px : ax;
    const float* sy = (t == 0) ? py : ay;

    float seg = 0.f, cons = 0.f;
#pragma unroll 4
    for (int j = 0; j < 256; ++j) {
        int r = (j - t) & 255;
        float dx = sx[j] - gx[r];
        float dy = sy[j] - gy[r];
        seg += dx * dx + dy * dy;
        float ex = px[j] - cx[r];
        float ey = py[j] - cy[r];
        cons += ex * ex + ey * ey;
    }
    seg  *= (1.0f / 512.0f);
    cons *= (1.0f / 512.0f);

#pragma unroll
    for (int off = 32; off > 0; off >>= 1) {
        seg  = fminf(seg,  __shfl_down(seg,  off));
        cons = fminf(cons, __shfl_down(cons, off));
    }
    __shared__ float rs[4], rc[4];
    int lane = t & 63, wid = t >> 6;
    if (lane == 0) { rs[wid] = seg; rc[wid] = cons; }
    __syncthreads();
    if (t == 0) {
        seg_min[b]  = fminf(fminf(rs[0], rs[1]), fminf(rs[2], rs[3]));
        cons_min[b] = fminf(fminf(rc[0], rc[1]), fminf(rc[2], rc[3]));
    }
}

// ---------------------------------------------------------------------------
// Kernel C: finalize. Reduce the 5 partial-sum arrays + seg/cons minima and
// compose the scalar loss.
// ---------------------------------------------------------------------------
__global__ __launch_bounds__(256) void final_kernel(
    const float* __restrict__ psum, const float* __restrict__ seg_min,
    const float* __restrict__ cons_min, float* __restrict__ out, int B)
{
    __shared__ float red[256];
    __shared__ float sums[5];
    __shared__ float seg_tot_sh;
    int t = threadIdx.x;

    for (int k = 0; k < 5; ++k) {
        float v = 0.f;
        for (int i = t; i < MASK_BLOCKS; i += 256) v += psum[k * MASK_BLOCKS + i];
        red[t] = v;
        __syncthreads();
        for (int off = 128; off > 0; off >>= 1) {
            if (t < off) red[t] += red[t + off];
            __syncthreads();
        }
        if (t == 0) sums[k] = red[0];
        __syncthreads();
    }

    // seg_min sum
    red[t] = (t < B) ? seg_min[t] : 0.f;
    __syncthreads();
    for (int off = 128; off > 0; off >>= 1) {
        if (t < off) red[t] += red[t + off];
        __syncthreads();
    }
    if (t == 0) seg_tot_sh = red[0];
    __syncthreads();

    // cons_min sum
    red[t] = (t < B) ? cons_min[t] : 0.f;
    __syncthreads();
    for (int off = 128; off > 0; off >>= 1) {
        if (t < off) red[t] += red[t + off];
        __syncthreads();
    }

    if (t == 0) {
        float cons_tot = red[0];
        float seg_tot  = seg_tot_sh;
        float S_cg = sums[0], S_cs = sums[1], S_c = sums[2],
              S_g  = sums[3], S_s  = sums[4];
        float dice1 = 1.f - (2.f * S_cg + SMOOTH) / (S_c + S_g + SMOOTH);
        float dice2 = 1.f - (2.f * S_cs + SMOOTH) / (S_c + S_s + SMOOTH);
        out[0] = dice1 + seg_tot + GAMMA * (dice2 + cons_tot);
    }
}

extern "C" void kernel_launch(void* const* d_in, const int* in_sizes, int n_in,
                              void* d_out, int out_size, void* d_ws, size_t ws_size,
                              hipStream_t stream) {
    const float* gt_mask = (const float*)d_in[0];   // [B,512,512]
    const float* gtc     = (const float*)d_in[1];   // [B,256,2]
    const float* sgs     = (const float*)d_in[2];   // [B,256,2]
    const float* scs     = (const float*)d_in[3];   // [B,256,2]
    const float* sn_mask = (const float*)d_in[4];   // [B,512,512]
    const float* cc      = (const float*)d_in[5];   // [B,256,2]
    const float* cl_mask = (const float*)d_in[6];   // [B,512,512]
    float* out = (float*)d_out;

    float* ws       = (float*)d_ws;
    float* psum     = ws;                      // 5 * MASK_BLOCKS floats
    float* seg_min  = ws + 5 * MASK_BLOCKS;    // B floats
    float* cons_min = seg_min + 64;            // B floats

    int n4 = in_sizes[0] / 4;                  // 4,194,304 float4s
    int B  = in_sizes[1] / 512;                // 64

    hipLaunchKernelGGL(mask_sums_kernel, dim3(MASK_BLOCKS), dim3(256), 0, stream,
                       (const float4*)gt_mask, (const float4*)sn_mask,
                       (const float4*)cl_mask, psum, n4);
    hipLaunchKernelGGL(contour_kernel, dim3(B), dim3(256), 0, stream,
                       (const float2*)gtc, (const float2*)sgs,
                       (const float2*)scs, (const float2*)cc,
                       seg_min, cons_min);
    hipLaunchKernelGGL(final_kernel, dim3(1), dim3(256), 0, stream,
                       psum, seg_min, cons_min, out, B);
}